// Round 15
// baseline (5304.631 us; speedup 1.0000x reference)
//
#include <hip/hip_runtime.h>

#define D      1024
#define BSZ    512
#define MC     256
#define NBK    64
#define NPAN   16
#define N_ROUNDS 3
#define MAXIT  30
#define TOLV   0.01f
#define RHOV   3.0f
#define XRHOV  0.5f
#define GRID   256
#define NGB    128   // group B: LU/solve blocks (bid < NGB)
#define NGA    128   // group A: Dykstra blocks (bid >= NGB)

// dyk LDS float offsets
#define TS   0
#define QS   4096
#define US   8192
#define PART 9216
#define BS   13312
#define RED  13568
#define SMF  13600

struct KArgs {
  const float *c, *A, *b, *AA, *L, *Lam;
  float *yout, *F, *Ybuf, *Wm;
  float *t, *At, *AAt;
  int *perm, *rmap;               // rmap: 16 panels x 64
  unsigned *slotsF, *slotsG, *errb;
};

// ---------------- fenced flat barrier ----------------
__device__ __forceinline__ void fbar(unsigned* slots, int lid, int count, unsigned target) {
  __syncthreads();
  if (threadIdx.x == 0) {
    __builtin_amdgcn_fence(__ATOMIC_RELEASE, "agent");
    __hip_atomic_store(&slots[lid * 16], target, __ATOMIC_RELAXED, __HIP_MEMORY_SCOPE_AGENT);
  }
  for (int i = threadIdx.x; i < count; i += 256)
    while (__hip_atomic_load(&slots[i * 16], __ATOMIC_RELAXED, __HIP_MEMORY_SCOPE_AGENT) < target)
      __builtin_amdgcn_s_sleep(1);
  __builtin_amdgcn_fence(__ATOMIC_ACQUIRE, "agent");
  __syncthreads();
}

// ---------------- shared tile FMA (64x64 tile, 4x4 per thread) ----------------
__device__ __forceinline__ void tile_fma(const float (*As)[68], const float (*Bs)[68],
                                         float acc[4][4], const int tx, const int ty) {
#pragma unroll 8
  for (int kk = 0; kk < 64; ++kk) {
    const float4 a4 = *(const float4*)(&As[kk][ty * 4]);
    const float4 b4 = *(const float4*)(&Bs[kk][tx * 4]);
    const float a0 = a4.x, a1 = a4.y, a2 = a4.z, a3 = a4.w;
    const float b0 = b4.x, b1 = b4.y, b2 = b4.z, b3 = b4.w;
    acc[0][0] = fmaf(a0, b0, acc[0][0]); acc[0][1] = fmaf(a0, b1, acc[0][1]);
    acc[0][2] = fmaf(a0, b2, acc[0][2]); acc[0][3] = fmaf(a0, b3, acc[0][3]);
    acc[1][0] = fmaf(a1, b0, acc[1][0]); acc[1][1] = fmaf(a1, b1, acc[1][1]);
    acc[1][2] = fmaf(a1, b2, acc[1][2]); acc[1][3] = fmaf(a1, b3, acc[1][3]);
    acc[2][0] = fmaf(a2, b0, acc[2][0]); acc[2][1] = fmaf(a2, b1, acc[2][1]);
    acc[2][2] = fmaf(a2, b2, acc[2][2]); acc[2][3] = fmaf(a2, b3, acc[2][3]);
    acc[3][0] = fmaf(a3, b0, acc[3][0]); acc[3][1] = fmaf(a3, b1, acc[3][1]);
    acc[3][2] = fmaf(a3, b2, acc[3][2]); acc[3][3] = fmaf(a3, b3, acc[3][3]);
  }
}

// ---------------- prep / transpose ----------------
__device__ void ph_prep(float* sm, int vb, const float* L, const float* Lam,
                        float* F, float* Ybuf) {
  float (*tile)[65] = (float(*)[65])sm;
  const int bi = vb >> 4, bj = vb & 15;
  const int tx = threadIdx.x & 63, ty4 = threadIdx.x >> 6;
  const int i0 = bi * 64, j0 = bj * 64;
  for (int r = ty4; r < 64; r += 4) {
    const float v = L[(size_t)(i0 + r) * D + j0 + tx];
    F[(size_t)(i0 + r) * D + j0 + tx] = v;
    tile[r][tx] = v;
  }
  __syncthreads();
  for (int r = ty4; r < 64; r += 4) {
    const int j = j0 + r;
    Ybuf[(size_t)j * D + i0 + tx] = Lam[j] * tile[tx][r];
  }
  __syncthreads();
}

__device__ void ph_transpose(float* sm, const float* src, float* dst,
                             int srows, int scols, int tr, int tc) {
  float (*tile)[65] = (float(*)[65])sm;
  const int tx = threadIdx.x & 63, ty = threadIdx.x >> 6;
  for (int r = ty; r < 64; r += 4)
    tile[r][tx] = src[(size_t)(tr * 64 + r) * scols + tc * 64 + tx];
  __syncthreads();
  for (int r = ty; r < 64; r += 4)
    dst[(size_t)(tc * 64 + r) * srows + tr * 64 + tx] = tile[tx][r];
  __syncthreads();
}

// ---------------- LU: LDS-only pivoting (2 syncs/column), deferred off-panel swaps ----------------
__device__ void ph_lu_diag(float* sm, float* F, int* perm, int* rmapk, int k) {
  float (*blk)[65] = (float(*)[65])sm;
  int* rmp = (int*)&sm[8964];
  const int tid = threadIdx.x;
  const int c0 = k * NBK;
  for (int e = tid; e < 4096; e += 256) {
    const int r = e >> 6, c = e & 63;
    blk[r][c] = F[(size_t)(c0 + r) * D + c0 + c];
  }
  if (tid < 64) rmp[tid] = tid;
  __syncthreads();
  for (int j = 0; j < 64; ++j) {
    if (tid < 64) {
      // butterfly argmax: all 64 lanes converge to (max, smallest index)
      float v = (tid >= j) ? fabsf(blk[tid][j]) : -1.0f;
      int ridx = tid;
      for (int off = 32; off > 0; off >>= 1) {
        const float ov = __shfl_xor(v, off);
        const int oi = __shfl_xor(ridx, off);
        if (ov > v || (ov == v && oi < ridx)) { v = ov; ridx = oi; }
      }
      const int pr = ridx;  // uniform across the wave
      if (pr != j) {
        const float aj = blk[j][tid], ap = blk[pr][tid];
        blk[j][tid] = ap; blk[pr][tid] = aj;
        if (tid == 0) {
          int t = perm[c0 + j]; perm[c0 + j] = perm[c0 + pr]; perm[c0 + pr] = t;
          t = rmp[j]; rmp[j] = rmp[pr]; rmp[pr] = t;
        }
      }
    }
    __syncthreads();
    const float inv = 1.0f / blk[j][j];
    const int r = tid >> 2, l4 = tid & 3;
    if (r > j) {
      const float lval = blk[r][j] * inv;
      if (l4 == 0) blk[r][j] = lval;
      for (int c = j + 1 + l4; c < 64; c += 4)
        blk[r][c] = fmaf(-lval, blk[j][c], blk[r][c]);
    }
    __syncthreads();
  }
  for (int e = tid; e < 4096; e += 256) {
    const int r = e >> 6, c = e & 63;
    F[(size_t)(c0 + r) * D + c0 + c] = blk[r][c];
  }
  if (tid < 64) rmapk[tid] = rmp[tid];
  __syncthreads();
}

__device__ void ph_leftperm(float* sm, float* F, const int* rmapk, int k, int chunk) {
  float (*tile)[65] = (float(*)[65])sm;
  int* rm = (int*)&sm[8960];
  const int tid = threadIdx.x;
  const int c0 = k * NBK;
  const int col0 = chunk * 64;
  if (tid < 64) rm[tid] = rmapk[tid];
  __syncthreads();
  for (int e = tid; e < 4096; e += 256) {
    const int r = e >> 6, c = e & 63;
    tile[r][c] = F[(size_t)(c0 + rm[r]) * D + col0 + c];
  }
  __syncthreads();
  for (int e = tid; e < 4096; e += 256) {
    const int r = e >> 6, c = e & 63;
    F[(size_t)(c0 + r) * D + col0 + c] = tile[r][c];
  }
  __syncthreads();
}

__device__ void ph_l21(float* sm, float* F, int k, int vb) {
  const int c0 = k * NBK;
  const int row0 = c0 + NBK;
  const int nrows = D - row0;
  float (*U)[65] = (float(*)[65])sm;
  const int tid = threadIdx.x;
  for (int e = tid; e < 4096; e += 256) { const int r = e >> 6, c = e & 63; U[r][c] = F[(size_t)(c0 + r) * D + c0 + c]; }
  __syncthreads();
  const int r = vb * 256 + tid;
  if (r < nrows) {
    float* Arow = &F[(size_t)(row0 + r) * D + c0];
    float x[64];
#pragma unroll
    for (int i = 0; i < 16; ++i) *(float4*)&x[i * 4] = *(const float4*)&Arow[i * 4];
#pragma unroll
    for (int jj = 0; jj < 64; ++jj) {
      float s0 = 0.f, s1 = 0.f, s2 = 0.f, s3 = 0.f;
#pragma unroll
      for (int i = 0; i + 3 < jj; i += 4) {
        s0 = fmaf(x[i], U[i][jj], s0);
        s1 = fmaf(x[i + 1], U[i + 1][jj], s1);
        s2 = fmaf(x[i + 2], U[i + 2][jj], s2);
        s3 = fmaf(x[i + 3], U[i + 3][jj], s3);
      }
#pragma unroll
      for (int i = (jj / 4) * 4; i < jj; ++i) s0 = fmaf(x[i], U[i][jj], s0);
      const float a = x[jj] - ((s0 + s1) + (s2 + s3));
      x[jj] = a / U[jj][jj];
    }
#pragma unroll
    for (int i = 0; i < 16; ++i) *(float4*)&Arow[i * 4] = *(const float4*)&x[i * 4];
  }
  __syncthreads();
}

__device__ void ph_trsm(float* sm, float* F, const int* rmapk, int k, int vb) {
  const int c0 = k * NBK;
  const int colstart = c0 + NBK;
  const int ncols = D - colstart;
  float (*Lw)[65] = (float(*)[65])sm;
  int* rm = (int*)&sm[8960];
  const int tid = threadIdx.x;
  for (int e = tid; e < 4096; e += 256) { const int r = e >> 6, c = e & 63; Lw[r][c] = F[(size_t)(c0 + r) * D + c0 + c]; }
  if (tid < 64) rm[tid] = rmapk[tid];
  __syncthreads();
  const int cidx = vb * 256 + tid;
  if (cidx < ncols) {
    const int col = colstart + cidx;
    float x[64];
#pragma unroll
    for (int i = 0; i < 64; ++i) x[i] = F[(size_t)(c0 + rm[i]) * D + col];
#pragma unroll
    for (int i = 0; i < 64; ++i) {
      float s0 = 0.f, s1 = 0.f, s2 = 0.f, s3 = 0.f;
#pragma unroll
      for (int j = 0; j + 3 < i; j += 4) {
        s0 = fmaf(Lw[i][j], x[j], s0);
        s1 = fmaf(Lw[i][j + 1], x[j + 1], s1);
        s2 = fmaf(Lw[i][j + 2], x[j + 2], s2);
        s3 = fmaf(Lw[i][j + 3], x[j + 3], s3);
      }
#pragma unroll
      for (int j = (i / 4) * 4; j < i; ++j) s0 = fmaf(Lw[i][j], x[j], s0);
      x[i] = x[i] - ((s0 + s1) + (s2 + s3));
    }
#pragma unroll
    for (int i = 0; i < 64; ++i) F[(size_t)(c0 + i) * D + col] = x[i];
  }
  __syncthreads();
}

__device__ void ph_gemm_nn(float* sm, float* F, int k, int vbx, int vby) {
  const int c0 = k * NBK;
  const int o = c0 + NBK;
  float (*As)[68] = (float(*)[68])sm;
  float (*Bs)[68] = (float(*)[68])&sm[4352];
  const int tid = threadIdx.x;
  const int cc0 = o + vbx * 64;
  const int r0 = o + vby * 64;
  for (int e = tid; e < 4096; e += 256) {
    const int r = e >> 6, c = e & 63;
    As[c][r] = F[(size_t)(r0 + r) * D + c0 + c];
    Bs[r][c] = F[(size_t)(c0 + r) * D + cc0 + c];
  }
  __syncthreads();
  float acc[4][4] = {};
  tile_fma(As, Bs, acc, tid & 15, tid >> 4);
  const int tx = tid & 15, ty = tid >> 4;
  for (int i = 0; i < 4; ++i)
    for (int j = 0; j < 4; ++j)
      F[(size_t)(r0 + ty * 4 + i) * D + cc0 + tx * 4 + j] -= acc[i][j];
  __syncthreads();
}

__device__ void ph_fsolve(float* sm, const float* F, float* Y, int k, int vb) {
  float (*T)[65] = (float(*)[65])sm;
  const int tid = threadIdx.x;
  const int c0 = k * NBK;
  for (int e = tid; e < 4096; e += 256) { const int r = e >> 6, c = e & 63; T[c][r] = F[(size_t)(c0 + r) * D + c0 + c]; }
  __syncthreads();
  const int col = vb * 256 + tid;
  float x[64];
#pragma unroll
  for (int i = 0; i < 64; ++i) x[i] = Y[(size_t)(c0 + i) * D + col];
#pragma unroll
  for (int i = 0; i < 64; ++i) {
    float s0 = 0.f, s1 = 0.f, s2 = 0.f, s3 = 0.f;
#pragma unroll
    for (int j = 0; j + 3 < i; j += 4) {
      s0 = fmaf(T[i][j], x[j], s0);
      s1 = fmaf(T[i][j + 1], x[j + 1], s1);
      s2 = fmaf(T[i][j + 2], x[j + 2], s2);
      s3 = fmaf(T[i][j + 3], x[j + 3], s3);
    }
#pragma unroll
    for (int j = (i / 4) * 4; j < i; ++j) s0 = fmaf(T[i][j], x[j], s0);
    const float a = x[i] - ((s0 + s1) + (s2 + s3));
    x[i] = a / T[i][i];
  }
#pragma unroll
  for (int i = 0; i < 64; ++i) Y[(size_t)(c0 + i) * D + col] = x[i];
  __syncthreads();
}

__device__ void ph_bsolve(float* sm, const float* F, float* Y, int k, int vb) {
  float (*T)[65] = (float(*)[65])sm;
  const int tid = threadIdx.x;
  const int c0 = k * NBK;
  for (int e = tid; e < 4096; e += 256) { const int r = e >> 6, c = e & 63; T[c][r] = F[(size_t)(c0 + r) * D + c0 + c]; }
  __syncthreads();
  const int col = vb * 256 + tid;
  float x[64];
#pragma unroll
  for (int i = 0; i < 64; ++i) x[i] = Y[(size_t)(c0 + i) * D + col];
#pragma unroll
  for (int i = 63; i >= 0; --i) {
    float s0 = 0.f, s1 = 0.f, s2 = 0.f, s3 = 0.f;
#pragma unroll
    for (int j = i + 1; j + 3 < 64; j += 4) {
      s0 = fmaf(T[i][j], x[j], s0);
      s1 = fmaf(T[i][j + 1], x[j + 1], s1);
      s2 = fmaf(T[i][j + 2], x[j + 2], s2);
      s3 = fmaf(T[i][j + 3], x[j + 3], s3);
    }
#pragma unroll
    for (int j = i + 1 + (((63 - i) / 4) * 4); j < 64; ++j) s0 = fmaf(T[i][j], x[j], s0);
    x[i] = x[i] - ((s0 + s1) + (s2 + s3));
  }
#pragma unroll
  for (int i = 0; i < 64; ++i) Y[(size_t)(c0 + i) * D + col] = x[i];
  __syncthreads();
}

__device__ void ph_tn(float* sm, const float* F, float* Y, int k, int rlo, int vbx, int vby) {
  const int c0 = k * NBK;
  float (*As)[68] = (float(*)[68])sm;
  float (*Bs)[68] = (float(*)[68])&sm[4352];
  const int tid = threadIdx.x;
  const int cc0 = vbx * 64;
  const int r0 = rlo + vby * 64;
  for (int e = tid; e < 4096; e += 256) {
    const int r = e >> 6, c = e & 63;
    As[r][c] = F[(size_t)(c0 + r) * D + r0 + c];
    Bs[r][c] = Y[(size_t)(c0 + r) * D + cc0 + c];
  }
  __syncthreads();
  float acc[4][4] = {};
  tile_fma(As, Bs, acc, tid & 15, tid >> 4);
  const int tx = tid & 15, ty = tid >> 4;
  for (int i = 0; i < 4; ++i)
    for (int j = 0; j < 4; ++j)
      Y[(size_t)(r0 + ty * 4 + i) * D + cc0 + tx * 4 + j] -= acc[i][j];
  __syncthreads();
}

__device__ void ph_scatter(const float* Y, float* Wm, const int* perm, int vb) {
  const int i = vb >> 2;
  const int c = (vb & 3) * 256 + threadIdx.x;
  Wm[(size_t)perm[i] * D + c] = Y[(size_t)i * D + c];
}

__device__ void ph_round(float* sm, const float* yout, const float* Wm, const float* cmat,
                         float* t, int vbx, int vby) {
  float (*As)[68] = (float(*)[68])sm;
  float (*Bs)[68] = (float(*)[68])&sm[4352];
  const int tid = threadIdx.x;
  const int i0 = vbx * 64;
  const int b0 = vby * 64;
  float acc[4][4] = {};
  for (int kb = 0; kb < D; kb += 64) {
    for (int e = tid; e < 4096; e += 256) {
      const int r = e >> 6, c = e & 63;
      As[c][r] = yout[(size_t)(b0 + r) * D + kb + c];
      Bs[r][c] = Wm[(size_t)(kb + r) * D + i0 + c];
    }
    __syncthreads();
    tile_fma(As, Bs, acc, tid & 15, tid >> 4);
    __syncthreads();
  }
  const int tx = tid & 15, ty = tid >> 4;
  for (int i = 0; i < 4; ++i)
    for (int j = 0; j < 4; ++j) {
      const int b = b0 + ty * 4 + i, col = i0 + tx * 4 + j;
      const float v = yout[(size_t)b * D + col] - XRHOV * acc[i][j] - RHOV * cmat[(size_t)b * D + col];
      t[(size_t)b * D + col] = v;
    }
  __syncthreads();
}

// ---------------- block-local Dykstra ----------------
template <int R>
__device__ void dyk_state_init(float* sm, const KArgs& a, int r0) {
  float4* ts4 = (float4*)(sm + TS);
  float4* qs4 = (float4*)(sm + QS);
  const float4* t4 = (const float4*)(a.t + (size_t)r0 * D);
  for (int e = threadIdx.x; e < R * 256; e += 256) {
    ts4[e] = t4[e];
    qs4[e] = make_float4(0.f, 0.f, 0.f, 0.f);
  }
  sm[BS + threadIdx.x] = a.b[threadIdx.x];
  __syncthreads();
}

template <int R>
__device__ void dyk_iter(float* sm, const KArgs& a, int r0) {
  const int tid = threadIdx.x;
  float* ts = sm + TS;
  float* qs = sm + QS;
  float* us = sm + US;
  float* part = sm + PART;

  const int m4 = tid & 63, ks = tid >> 6;
  const float* AtB = a.At + (size_t)ks * 256 * MC + m4 * 4;
  float4 ua[R];
#pragma unroll
  for (int r = 0; r < R; ++r) ua[r] = make_float4(0.f, 0.f, 0.f, 0.f);
  const int kb = ks * 256;
#pragma unroll 2
  for (int k4 = 0; k4 < 64; ++k4) {
    float tr[R][4];
#pragma unroll
    for (int r = 0; r < R; ++r) *(float4*)tr[r] = *(const float4*)&ts[r * 1024 + kb + k4 * 4];
#pragma unroll
    for (int j = 0; j < 4; ++j) {
      const float4 av = *(const float4*)(AtB + (size_t)(k4 * 4 + j) * MC);
#pragma unroll
      for (int r = 0; r < R; ++r) {
        ua[r].x = fmaf(tr[r][j], av.x, ua[r].x);
        ua[r].y = fmaf(tr[r][j], av.y, ua[r].y);
        ua[r].z = fmaf(tr[r][j], av.z, ua[r].z);
        ua[r].w = fmaf(tr[r][j], av.w, ua[r].w);
      }
    }
  }
#pragma unroll
  for (int r = 0; r < R; ++r) ((float4*)part)[(ks * R + r) * 64 + m4] = ua[r];
  __syncthreads();

  {
    const int m = tid;
#pragma unroll
    for (int r = 0; r < R; ++r)
      us[r * 256 + m] = part[(0 * R + r) * 256 + m] + part[(1 * R + r) * 256 + m] +
                        part[(2 * R + r) * 256 + m] + part[(3 * R + r) * 256 + m] - sm[BS + m];
  }
  __syncthreads();

  float4 ya[R];
#pragma unroll
  for (int r = 0; r < R; ++r) ya[r] = make_float4(0.f, 0.f, 0.f, 0.f);
  const float4* AAB = (const float4*)a.AAt;
#pragma unroll 2
  for (int mi = 0; mi < 64; ++mi) {
    float ur[R][4];
#pragma unroll
    for (int r = 0; r < R; ++r) *(float4*)ur[r] = *(const float4*)&us[r * 256 + mi * 4];
#pragma unroll
    for (int j = 0; j < 4; ++j) {
      const float4 w = AAB[(size_t)(mi * 4 + j) * (D / 4) + tid];
#pragma unroll
      for (int r = 0; r < R; ++r) {
        ya[r].x = fmaf(ur[r][j], w.x, ya[r].x);
        ya[r].y = fmaf(ur[r][j], w.y, ya[r].y);
        ya[r].z = fmaf(ur[r][j], w.z, ya[r].z);
        ya[r].w = fmaf(ur[r][j], w.w, ya[r].w);
      }
    }
  }

  float nmax = 0.f;
#pragma unroll
  for (int r = 0; r < R; ++r) {
    const float4 tv = *(const float4*)&ts[r * 1024 + tid * 4];
    float4 y;
    y.x = tv.x - ya[r].x; y.y = tv.y - ya[r].y;
    y.z = tv.z - ya[r].z; y.w = tv.w - ya[r].w;
    ((float4*)a.yout)[(size_t)(r0 + r) * (D / 4) + tid] = y;
    const float4 qv = *(const float4*)&qs[r * 1024 + tid * 4];
    float4 tn, qn;
    { const float yq = y.x + qv.x, xn = fmaxf(yq, 0.f); tn.x = xn + (tv.x - y.x); qn.x = yq - xn; }
    { const float yq = y.y + qv.y, xn = fmaxf(yq, 0.f); tn.y = xn + (tv.y - y.y); qn.y = yq - xn; }
    { const float yq = y.z + qv.z, xn = fmaxf(yq, 0.f); tn.z = xn + (tv.z - y.z); qn.z = yq - xn; }
    { const float yq = y.w + qv.w, xn = fmaxf(yq, 0.f); tn.w = xn + (tv.w - y.w); qn.w = yq - xn; }
    *(float4*)&ts[r * 1024 + tid * 4] = tn;
    *(float4*)&qs[r * 1024 + tid * 4] = qn;
    nmax = fmaxf(nmax, -y.x); nmax = fmaxf(nmax, -y.y);
    nmax = fmaxf(nmax, -y.z); nmax = fmaxf(nmax, -y.w);
  }
#pragma unroll
  for (int off = 32; off > 0; off >>= 1) nmax = fmaxf(nmax, __shfl_down(nmax, off));
  if ((tid & 63) == 0) sm[RED + (tid >> 6)] = nmax;
  __syncthreads();
}

// fence-free round: per-iteration sync via per-block posted err slots
template <int R>
__device__ void dyk_round(float* sm, const KArgs& a, int lid, int nblk, int base) {
  const int r0 = lid * R;
  dyk_state_init<R>(sm, a, r0);
  for (int it = 0; it < MAXIT; ++it) {
    dyk_iter<R>(sm, a, r0);
    if (threadIdx.x == 0) {
      const float bmax = fmaxf(fmaxf(sm[RED], sm[RED + 1]), fmaxf(sm[RED + 2], sm[RED + 3]));
      __hip_atomic_store(&a.errb[(size_t)(base + it) * GRID + lid],
                         __float_as_uint(bmax) | 0x80000000u,
                         __ATOMIC_RELAXED, __HIP_MEMORY_SCOPE_AGENT);
    }
    float v = 0.f;
    if (threadIdx.x < nblk) {
      unsigned u = __hip_atomic_load(&a.errb[(size_t)(base + it) * GRID + threadIdx.x],
                                     __ATOMIC_RELAXED, __HIP_MEMORY_SCOPE_AGENT);
      while (!(u & 0x80000000u)) {
        __builtin_amdgcn_s_sleep(1);
        u = __hip_atomic_load(&a.errb[(size_t)(base + it) * GRID + threadIdx.x],
                              __ATOMIC_RELAXED, __HIP_MEMORY_SCOPE_AGENT);
      }
      v = __uint_as_float(u & 0x7FFFFFFFu);
    }
#pragma unroll
    for (int off = 32; off > 0; off >>= 1) v = fmaxf(v, __shfl_down(v, off));
    __syncthreads();
    if ((threadIdx.x & 63) == 0) sm[RED + (threadIdx.x >> 6)] = v;
    __syncthreads();
    const float gmax = fmaxf(fmaxf(sm[RED], sm[RED + 1]), fmaxf(sm[RED + 2], sm[RED + 3]));
    __syncthreads();
    if (gmax < TOLV) break;
  }
}

// ---------------- the megakernel ----------------
__global__ __launch_bounds__(256, 1) void mega(KArgs a) {
  __shared__ alignas(16) float sm[SMF];
  const int bid = blockIdx.x;
  const int tid = threadIdx.x;
  unsigned genF = 0, genG = 0;

  // ---- joint init ----
  {
    const int gtid = bid * 256 + tid;
    for (int i = gtid; i < BSZ * D; i += GRID * 256) a.t[i] = -RHOV * a.c[i];
    if (gtid < D) a.perm[gtid] = gtid;
  }
  for (int vb = bid; vb < 384; vb += GRID) {
    if (vb < 256) ph_prep(sm, vb, a.L, a.Lam, a.F, a.Ybuf);
    else if (vb < 320) { const int tt = vb - 256; ph_transpose(sm, a.A, a.At, MC, D, tt & 3, tt >> 2); }
    else { const int tt = vb - 320; ph_transpose(sm, a.AA, a.AAt, D, MC, tt & 15, tt >> 4); }
  }
  if (bid == 0) {  // panel-0 diag tile was written by this very block (vb==0)
    __threadfence_block();
    __syncthreads();
    ph_lu_diag(sm, a.F, a.perm, a.rmap, 0);
  }
  fbar(a.slotsF, bid, GRID, ++genF);

  if (bid < NGB) {
    // ======== group B: LU (2 barriers/panel) + piggybacked forward solve ========
    unsigned* slotsB = a.slotsG;
    const int vbid = bid;
    for (int k = 0; k < NPAN; ++k) {
      const int rem = D - (k + 1) * NBK;
      const int nvb = (rem > 0) ? (rem + 255) / 256 : 0;
      // P1: leftperm | l21 | trsm | fsolve(k)
      const int ntask = k + 2 * nvb + 4;
      for (int vb = vbid; vb < ntask; vb += NGB) {
        if (vb < k) ph_leftperm(sm, a.F, a.rmap + k * 64, k, vb);
        else if (vb < k + nvb) ph_l21(sm, a.F, k, vb - k);
        else if (vb < k + 2 * nvb) ph_trsm(sm, a.F, a.rmap + k * 64, k, vb - k - nvb);
        else ph_fsolve(sm, a.F, a.Ybuf, k, vb - k - 2 * nvb);
      }
      fbar(slotsB, vbid, NGB, ++genG);
      // P2: block 0 -> trailing tile (0,0) then lu_diag(k+1) immediately;
      //     blocks 1..127 -> remaining gemm tiles + forward-solve tn tasks
      if (rem > 0) {
        const int nt = rem / 64;
        const int ntask2 = nt * nt + 16 * nt;
        if (vbid == 0) {
          ph_gemm_nn(sm, a.F, k, 0, 0);  // the (k+1,k+1) diag tile
          __threadfence_block();
          __syncthreads();
          ph_lu_diag(sm, a.F, a.perm, a.rmap + (k + 1) * 64, k + 1);
        } else {
          for (int vb = vbid; vb < ntask2; vb += NGB - 1) {
            if (vb < nt * nt) ph_gemm_nn(sm, a.F, k, vb % nt, vb / nt);
            else { const int t2 = vb - nt * nt; ph_tn(sm, a.F, a.Ybuf, k, (k + 1) * NBK, t2 & 15, t2 >> 4); }
          }
        }
        fbar(slotsB, vbid, NGB, ++genG);
      }
    }
    // ---- backward solve (barrier-phase form, verified) ----
    for (int k = NPAN - 1; k >= 0; --k) {
      for (int vb = vbid; vb < 4; vb += NGB) ph_bsolve(sm, a.F, a.Ybuf, k, vb);
      fbar(slotsB, vbid, NGB, ++genG);
      if (k > 0) {
        for (int vb = vbid; vb < 16 * k; vb += NGB)
          ph_tn(sm, a.F, a.Ybuf, k, 0, vb & 15, vb >> 4);
        fbar(slotsB, vbid, NGB, ++genG);
      }
    }
    for (int vb = vbid; vb < 4 * D; vb += NGB) ph_scatter(a.Ybuf, a.Wm, a.perm, vb);
    fbar(a.slotsF, bid, GRID, ++genF);  // join: Wm published
  } else {
    // ======== group A: round-0 Dykstra (overlaps group B) ========
    dyk_round<4>(sm, a, bid - NGB, NGA, 0);
    fbar(a.slotsF, bid, GRID, ++genF);  // join
  }

  // ======== rounds 1,2: ph_round on B-blocks; Dykstra R=4 on A-blocks ========
  for (int r = 1; r < N_ROUNDS; ++r) {
    if (bid < 128) ph_round(sm, a.yout, a.Wm, a.c, a.t, bid & 15, bid >> 4);
    fbar(a.slotsF, bid, GRID, ++genF);  // t ready
    if (bid >= NGB) dyk_round<4>(sm, a, bid - NGB, NGA, r * MAXIT);
    if (r + 1 < N_ROUNDS)
      fbar(a.slotsF, bid, GRID, ++genF);  // yout ready for next ph_round
  }
}

extern "C" void kernel_launch(void* const* d_in, const int* in_sizes, int n_in,
                              void* d_out, int out_size, void* d_ws, size_t ws_size,
                              hipStream_t stream) {
  (void)in_sizes; (void)n_in; (void)out_size; (void)ws_size;
  KArgs a;
  a.c   = (const float*)d_in[0];
  a.A   = (const float*)d_in[1];
  a.b   = (const float*)d_in[2];
  a.AA  = (const float*)d_in[3];
  a.L   = (const float*)d_in[4];
  a.Lam = (const float*)d_in[5];
  a.yout = (float*)d_out;

  // ctrl region (zeroed every call; ws is NOT re-poisoned between replays)
  char* w = (char*)d_ws;
  a.slotsF = (unsigned*)w;                    // 256 x 64B
  a.slotsG = (unsigned*)(w + 16384);          // 128 x 64B (B domain)
  a.errb   = (unsigned*)(w + 32768);          // 90 x 256 posted-err slots
  a.rmap   = (int*)(w + 124928);              // 16 x 64 ints
  w += 131072;
  a.F    = (float*)w; w += (size_t)D * D * 4;
  a.Ybuf = (float*)w; w += (size_t)D * D * 4;
  a.Wm   = (float*)w; w += (size_t)D * D * 4;
  a.t    = (float*)w; w += (size_t)BSZ * D * 4;
  a.At   = (float*)w; w += (size_t)D * MC * 4;
  a.AAt  = (float*)w; w += (size_t)MC * D * 4;
  a.perm = (int*)w;   w += (size_t)D * 4;

  hipMemsetAsync(d_ws, 0, 131072, stream);
  mega<<<dim3(GRID), dim3(256), 0, stream>>>(a);
}

// Round 16
// 5147.396 us; speedup vs baseline: 1.0305x; 1.0305x over previous
//
#include <hip/hip_runtime.h>

#define D      1024
#define BSZ    512
#define MC     256
#define NBK    64
#define NPAN   16
#define N_ROUNDS 3
#define MAXIT  30
#define TOLV   0.01f
#define RHOV   3.0f
#define XRHOV  0.5f
#define GRID   256
#define NGB    128   // group B: LU/solve blocks (bid < NGB)
#define NGA    128   // group A: Dykstra blocks (bid >= NGB)

// dyk LDS float offsets
#define TS   0
#define QS   4096
#define US   8192
#define PART 9216
#define BS   13312
#define RED  13568
#define SMF  13600

struct KArgs {
  const float *c, *A, *b, *AA, *L, *Lam;
  float *yout, *F, *Ybuf, *Wm;
  float *t, *At, *AAt;
  int *perm, *rmap;               // rmap: 16 panels x 64
  unsigned *slotsF, *slotsG, *errb;
};

// ---------------- fenced flat barrier ----------------
__device__ __forceinline__ void fbar(unsigned* slots, int lid, int count, unsigned target) {
  __syncthreads();
  if (threadIdx.x == 0) {
    __builtin_amdgcn_fence(__ATOMIC_RELEASE, "agent");
    __hip_atomic_store(&slots[lid * 16], target, __ATOMIC_RELAXED, __HIP_MEMORY_SCOPE_AGENT);
  }
  for (int i = threadIdx.x; i < count; i += 256)
    while (__hip_atomic_load(&slots[i * 16], __ATOMIC_RELAXED, __HIP_MEMORY_SCOPE_AGENT) < target)
      __builtin_amdgcn_s_sleep(1);
  __builtin_amdgcn_fence(__ATOMIC_ACQUIRE, "agent");
  __syncthreads();
}

// ---------------- shared tile FMA (64x64 tile, 4x4 per thread) ----------------
__device__ __forceinline__ void tile_fma(const float (*As)[68], const float (*Bs)[68],
                                         float acc[4][4], const int tx, const int ty) {
#pragma unroll 8
  for (int kk = 0; kk < 64; ++kk) {
    const float4 a4 = *(const float4*)(&As[kk][ty * 4]);
    const float4 b4 = *(const float4*)(&Bs[kk][tx * 4]);
    const float a0 = a4.x, a1 = a4.y, a2 = a4.z, a3 = a4.w;
    const float b0 = b4.x, b1 = b4.y, b2 = b4.z, b3 = b4.w;
    acc[0][0] = fmaf(a0, b0, acc[0][0]); acc[0][1] = fmaf(a0, b1, acc[0][1]);
    acc[0][2] = fmaf(a0, b2, acc[0][2]); acc[0][3] = fmaf(a0, b3, acc[0][3]);
    acc[1][0] = fmaf(a1, b0, acc[1][0]); acc[1][1] = fmaf(a1, b1, acc[1][1]);
    acc[1][2] = fmaf(a1, b2, acc[1][2]); acc[1][3] = fmaf(a1, b3, acc[1][3]);
    acc[2][0] = fmaf(a2, b0, acc[2][0]); acc[2][1] = fmaf(a2, b1, acc[2][1]);
    acc[2][2] = fmaf(a2, b2, acc[2][2]); acc[2][3] = fmaf(a2, b3, acc[2][3]);
    acc[3][0] = fmaf(a3, b0, acc[3][0]); acc[3][1] = fmaf(a3, b1, acc[3][1]);
    acc[3][2] = fmaf(a3, b2, acc[3][2]); acc[3][3] = fmaf(a3, b3, acc[3][3]);
  }
}

// ---------------- prep / transpose ----------------
__device__ void ph_prep(float* sm, int vb, const float* L, const float* Lam,
                        float* F, float* Ybuf) {
  float (*tile)[65] = (float(*)[65])sm;
  const int bi = vb >> 4, bj = vb & 15;
  const int tx = threadIdx.x & 63, ty4 = threadIdx.x >> 6;
  const int i0 = bi * 64, j0 = bj * 64;
  for (int r = ty4; r < 64; r += 4) {
    const float v = L[(size_t)(i0 + r) * D + j0 + tx];
    F[(size_t)(i0 + r) * D + j0 + tx] = v;
    tile[r][tx] = v;
  }
  __syncthreads();
  for (int r = ty4; r < 64; r += 4) {
    const int j = j0 + r;
    Ybuf[(size_t)j * D + i0 + tx] = Lam[j] * tile[tx][r];
  }
  __syncthreads();
}

__device__ void ph_transpose(float* sm, const float* src, float* dst,
                             int srows, int scols, int tr, int tc) {
  float (*tile)[65] = (float(*)[65])sm;
  const int tx = threadIdx.x & 63, ty = threadIdx.x >> 6;
  for (int r = ty; r < 64; r += 4)
    tile[r][tx] = src[(size_t)(tr * 64 + r) * scols + tc * 64 + tx];
  __syncthreads();
  for (int r = ty; r < 64; r += 4)
    dst[(size_t)(tc * 64 + r) * srows + tr * 64 + tx] = tile[tx][r];
  __syncthreads();
}

// ---------------- LU: LDS-only pivoting, deferred off-panel swaps ----------------
__device__ void ph_lu_diag(float* sm, float* F, int* perm, int* rmapk, int k) {
  float (*blk)[65] = (float(*)[65])sm;
  int* pr_sh = (int*)&sm[8960];
  int* rmp   = (int*)&sm[8964];
  const int tid = threadIdx.x;
  const int c0 = k * NBK;
  for (int e = tid; e < 4096; e += 256) {
    const int r = e >> 6, c = e & 63;
    blk[r][c] = F[(size_t)(c0 + r) * D + c0 + c];
  }
  if (tid < 64) rmp[tid] = tid;
  __syncthreads();
  for (int j = 0; j < 64; ++j) {
    if (tid < 64) {
      float v = (tid >= j) ? fabsf(blk[tid][j]) : -1.0f;
      int ridx = tid;
      for (int off = 32; off > 0; off >>= 1) {
        const float ov = __shfl_down(v, off);
        const int oi = __shfl_down(ridx, off);
        if (ov > v) { v = ov; ridx = oi; }
      }
      if (tid == 0) *pr_sh = ridx;
    }
    __syncthreads();
    const int pr = *pr_sh;
    if (pr != j) {
      if (tid < 64) { const float a = blk[j][tid], b = blk[pr][tid]; blk[j][tid] = b; blk[pr][tid] = a; }
      if (tid == 0) {
        int t = perm[c0 + j]; perm[c0 + j] = perm[c0 + pr]; perm[c0 + pr] = t;
        t = rmp[j]; rmp[j] = rmp[pr]; rmp[pr] = t;
      }
    }
    __syncthreads();
    const float inv = 1.0f / blk[j][j];
    const int r = tid >> 2, l4 = tid & 3;
    if (r > j) {
      const float lval = blk[r][j] * inv;
      if (l4 == 0) blk[r][j] = lval;
      for (int c = j + 1 + l4; c < 64; c += 4)
        blk[r][c] = fmaf(-lval, blk[j][c], blk[r][c]);
    }
    __syncthreads();
  }
  for (int e = tid; e < 4096; e += 256) {
    const int r = e >> 6, c = e & 63;
    F[(size_t)(c0 + r) * D + c0 + c] = blk[r][c];
  }
  if (tid < 64) rmapk[tid] = rmp[tid];
  __syncthreads();
}

__device__ void ph_leftperm(float* sm, float* F, const int* rmapk, int k, int chunk) {
  float (*tile)[65] = (float(*)[65])sm;
  int* rm = (int*)&sm[8960];
  const int tid = threadIdx.x;
  const int c0 = k * NBK;
  const int col0 = chunk * 64;
  if (tid < 64) rm[tid] = rmapk[tid];
  __syncthreads();
  for (int e = tid; e < 4096; e += 256) {
    const int r = e >> 6, c = e & 63;
    tile[r][c] = F[(size_t)(c0 + rm[r]) * D + col0 + c];
  }
  __syncthreads();
  for (int e = tid; e < 4096; e += 256) {
    const int r = e >> 6, c = e & 63;
    F[(size_t)(c0 + r) * D + col0 + c] = tile[r][c];
  }
  __syncthreads();
}

__device__ void ph_l21(float* sm, float* F, int k, int vb) {
  const int c0 = k * NBK;
  const int row0 = c0 + NBK;
  const int nrows = D - row0;
  float (*U)[65] = (float(*)[65])sm;
  const int tid = threadIdx.x;
  for (int e = tid; e < 4096; e += 256) { const int r = e >> 6, c = e & 63; U[r][c] = F[(size_t)(c0 + r) * D + c0 + c]; }
  __syncthreads();
  const int r = vb * 256 + tid;
  if (r < nrows) {
    float* Arow = &F[(size_t)(row0 + r) * D + c0];
    float x[64];
#pragma unroll
    for (int i = 0; i < 16; ++i) *(float4*)&x[i * 4] = *(const float4*)&Arow[i * 4];
#pragma unroll
    for (int jj = 0; jj < 64; ++jj) {
      float s0 = 0.f, s1 = 0.f, s2 = 0.f, s3 = 0.f;
#pragma unroll
      for (int i = 0; i + 3 < jj; i += 4) {
        s0 = fmaf(x[i], U[i][jj], s0);
        s1 = fmaf(x[i + 1], U[i + 1][jj], s1);
        s2 = fmaf(x[i + 2], U[i + 2][jj], s2);
        s3 = fmaf(x[i + 3], U[i + 3][jj], s3);
      }
#pragma unroll
      for (int i = (jj / 4) * 4; i < jj; ++i) s0 = fmaf(x[i], U[i][jj], s0);
      const float a = x[jj] - ((s0 + s1) + (s2 + s3));
      x[jj] = a / U[jj][jj];
    }
#pragma unroll
    for (int i = 0; i < 16; ++i) *(float4*)&Arow[i * 4] = *(const float4*)&x[i * 4];
  }
  __syncthreads();
}

__device__ void ph_trsm(float* sm, float* F, const int* rmapk, int k, int vb) {
  const int c0 = k * NBK;
  const int colstart = c0 + NBK;
  const int ncols = D - colstart;
  float (*Lw)[65] = (float(*)[65])sm;
  int* rm = (int*)&sm[8960];
  const int tid = threadIdx.x;
  for (int e = tid; e < 4096; e += 256) { const int r = e >> 6, c = e & 63; Lw[r][c] = F[(size_t)(c0 + r) * D + c0 + c]; }
  if (tid < 64) rm[tid] = rmapk[tid];
  __syncthreads();
  const int cidx = vb * 256 + tid;
  if (cidx < ncols) {
    const int col = colstart + cidx;
    float x[64];
#pragma unroll
    for (int i = 0; i < 64; ++i) x[i] = F[(size_t)(c0 + rm[i]) * D + col];
#pragma unroll
    for (int i = 0; i < 64; ++i) {
      float s0 = 0.f, s1 = 0.f, s2 = 0.f, s3 = 0.f;
#pragma unroll
      for (int j = 0; j + 3 < i; j += 4) {
        s0 = fmaf(Lw[i][j], x[j], s0);
        s1 = fmaf(Lw[i][j + 1], x[j + 1], s1);
        s2 = fmaf(Lw[i][j + 2], x[j + 2], s2);
        s3 = fmaf(Lw[i][j + 3], x[j + 3], s3);
      }
#pragma unroll
      for (int j = (i / 4) * 4; j < i; ++j) s0 = fmaf(Lw[i][j], x[j], s0);
      x[i] = x[i] - ((s0 + s1) + (s2 + s3));
    }
#pragma unroll
    for (int i = 0; i < 64; ++i) F[(size_t)(c0 + i) * D + col] = x[i];
  }
  __syncthreads();
}

__device__ void ph_gemm_nn(float* sm, float* F, int k, int vbx, int vby) {
  const int c0 = k * NBK;
  const int o = c0 + NBK;
  float (*As)[68] = (float(*)[68])sm;
  float (*Bs)[68] = (float(*)[68])&sm[4352];
  const int tid = threadIdx.x;
  const int cc0 = o + vbx * 64;
  const int r0 = o + vby * 64;
  for (int e = tid; e < 4096; e += 256) {
    const int r = e >> 6, c = e & 63;
    As[c][r] = F[(size_t)(r0 + r) * D + c0 + c];
    Bs[r][c] = F[(size_t)(c0 + r) * D + cc0 + c];
  }
  __syncthreads();
  float acc[4][4] = {};
  tile_fma(As, Bs, acc, tid & 15, tid >> 4);
  const int tx = tid & 15, ty = tid >> 4;
  for (int i = 0; i < 4; ++i)
    for (int j = 0; j < 4; ++j)
      F[(size_t)(r0 + ty * 4 + i) * D + cc0 + tx * 4 + j] -= acc[i][j];
  __syncthreads();
}

__device__ void ph_fsolve(float* sm, const float* F, float* Y, int k, int vb) {
  float (*T)[65] = (float(*)[65])sm;
  const int tid = threadIdx.x;
  const int c0 = k * NBK;
  for (int e = tid; e < 4096; e += 256) { const int r = e >> 6, c = e & 63; T[c][r] = F[(size_t)(c0 + r) * D + c0 + c]; }
  __syncthreads();
  const int col = vb * 256 + tid;
  float x[64];
#pragma unroll
  for (int i = 0; i < 64; ++i) x[i] = Y[(size_t)(c0 + i) * D + col];
#pragma unroll
  for (int i = 0; i < 64; ++i) {
    float s0 = 0.f, s1 = 0.f, s2 = 0.f, s3 = 0.f;
#pragma unroll
    for (int j = 0; j + 3 < i; j += 4) {
      s0 = fmaf(T[i][j], x[j], s0);
      s1 = fmaf(T[i][j + 1], x[j + 1], s1);
      s2 = fmaf(T[i][j + 2], x[j + 2], s2);
      s3 = fmaf(T[i][j + 3], x[j + 3], s3);
    }
#pragma unroll
    for (int j = (i / 4) * 4; j < i; ++j) s0 = fmaf(T[i][j], x[j], s0);
    const float a = x[i] - ((s0 + s1) + (s2 + s3));
    x[i] = a / T[i][i];
  }
#pragma unroll
  for (int i = 0; i < 64; ++i) Y[(size_t)(c0 + i) * D + col] = x[i];
  __syncthreads();
}

__device__ void ph_bsolve(float* sm, const float* F, float* Y, int k, int vb) {
  float (*T)[65] = (float(*)[65])sm;
  const int tid = threadIdx.x;
  const int c0 = k * NBK;
  for (int e = tid; e < 4096; e += 256) { const int r = e >> 6, c = e & 63; T[c][r] = F[(size_t)(c0 + r) * D + c0 + c]; }
  __syncthreads();
  const int col = vb * 256 + tid;
  float x[64];
#pragma unroll
  for (int i = 0; i < 64; ++i) x[i] = Y[(size_t)(c0 + i) * D + col];
#pragma unroll
  for (int i = 63; i >= 0; --i) {
    float s0 = 0.f, s1 = 0.f, s2 = 0.f, s3 = 0.f;
#pragma unroll
    for (int j = i + 1; j + 3 < 64; j += 4) {
      s0 = fmaf(T[i][j], x[j], s0);
      s1 = fmaf(T[i][j + 1], x[j + 1], s1);
      s2 = fmaf(T[i][j + 2], x[j + 2], s2);
      s3 = fmaf(T[i][j + 3], x[j + 3], s3);
    }
#pragma unroll
    for (int j = i + 1 + (((63 - i) / 4) * 4); j < 64; ++j) s0 = fmaf(T[i][j], x[j], s0);
    x[i] = x[i] - ((s0 + s1) + (s2 + s3));
  }
#pragma unroll
  for (int i = 0; i < 64; ++i) Y[(size_t)(c0 + i) * D + col] = x[i];
  __syncthreads();
}

__device__ void ph_tn(float* sm, const float* F, float* Y, int k, int rlo, int vbx, int vby) {
  const int c0 = k * NBK;
  float (*As)[68] = (float(*)[68])sm;
  float (*Bs)[68] = (float(*)[68])&sm[4352];
  const int tid = threadIdx.x;
  const int cc0 = vbx * 64;
  const int r0 = rlo + vby * 64;
  for (int e = tid; e < 4096; e += 256) {
    const int r = e >> 6, c = e & 63;
    As[r][c] = F[(size_t)(c0 + r) * D + r0 + c];
    Bs[r][c] = Y[(size_t)(c0 + r) * D + cc0 + c];
  }
  __syncthreads();
  float acc[4][4] = {};
  tile_fma(As, Bs, acc, tid & 15, tid >> 4);
  const int tx = tid & 15, ty = tid >> 4;
  for (int i = 0; i < 4; ++i)
    for (int j = 0; j < 4; ++j)
      Y[(size_t)(r0 + ty * 4 + i) * D + cc0 + tx * 4 + j] -= acc[i][j];
  __syncthreads();
}

__device__ void ph_scatter(const float* Y, float* Wm, const int* perm, int vb) {
  const int i = vb >> 2;
  const int c = (vb & 3) * 256 + threadIdx.x;
  Wm[(size_t)perm[i] * D + c] = Y[(size_t)i * D + c];
}

__device__ void ph_round(float* sm, const float* yout, const float* Wm, const float* cmat,
                         float* t, int vbx, int vby) {
  float (*As)[68] = (float(*)[68])sm;
  float (*Bs)[68] = (float(*)[68])&sm[4352];
  const int tid = threadIdx.x;
  const int i0 = vbx * 64;
  const int b0 = vby * 64;
  float acc[4][4] = {};
  for (int kb = 0; kb < D; kb += 64) {
    for (int e = tid; e < 4096; e += 256) {
      const int r = e >> 6, c = e & 63;
      As[c][r] = yout[(size_t)(b0 + r) * D + kb + c];
      Bs[r][c] = Wm[(size_t)(kb + r) * D + i0 + c];
    }
    __syncthreads();
    tile_fma(As, Bs, acc, tid & 15, tid >> 4);
    __syncthreads();
  }
  const int tx = tid & 15, ty = tid >> 4;
  for (int i = 0; i < 4; ++i)
    for (int j = 0; j < 4; ++j) {
      const int b = b0 + ty * 4 + i, col = i0 + tx * 4 + j;
      const float v = yout[(size_t)b * D + col] - XRHOV * acc[i][j] - RHOV * cmat[(size_t)b * D + col];
      t[(size_t)b * D + col] = v;
    }
  __syncthreads();
}

// ---------------- block-local Dykstra ----------------
template <int R>
__device__ void dyk_state_init(float* sm, const KArgs& a, int r0) {
  float4* ts4 = (float4*)(sm + TS);
  float4* qs4 = (float4*)(sm + QS);
  const float4* t4 = (const float4*)(a.t + (size_t)r0 * D);
  for (int e = threadIdx.x; e < R * 256; e += 256) {
    ts4[e] = t4[e];
    qs4[e] = make_float4(0.f, 0.f, 0.f, 0.f);
  }
  sm[BS + threadIdx.x] = a.b[threadIdx.x];
  __syncthreads();
}

template <int R>
__device__ void dyk_iter(float* sm, const KArgs& a, int r0) {
  const int tid = threadIdx.x;
  float* ts = sm + TS;
  float* qs = sm + QS;
  float* us = sm + US;
  float* part = sm + PART;

  const int m4 = tid & 63, ks = tid >> 6;
  const float* AtB = a.At + (size_t)ks * 256 * MC + m4 * 4;
  float4 ua[R];
#pragma unroll
  for (int r = 0; r < R; ++r) ua[r] = make_float4(0.f, 0.f, 0.f, 0.f);
  const int kb = ks * 256;
#pragma unroll 2
  for (int k4 = 0; k4 < 64; ++k4) {
    float tr[R][4];
#pragma unroll
    for (int r = 0; r < R; ++r) *(float4*)tr[r] = *(const float4*)&ts[r * 1024 + kb + k4 * 4];
#pragma unroll
    for (int j = 0; j < 4; ++j) {
      const float4 av = *(const float4*)(AtB + (size_t)(k4 * 4 + j) * MC);
#pragma unroll
      for (int r = 0; r < R; ++r) {
        ua[r].x = fmaf(tr[r][j], av.x, ua[r].x);
        ua[r].y = fmaf(tr[r][j], av.y, ua[r].y);
        ua[r].z = fmaf(tr[r][j], av.z, ua[r].z);
        ua[r].w = fmaf(tr[r][j], av.w, ua[r].w);
      }
    }
  }
#pragma unroll
  for (int r = 0; r < R; ++r) ((float4*)part)[(ks * R + r) * 64 + m4] = ua[r];
  __syncthreads();

  {
    const int m = tid;
#pragma unroll
    for (int r = 0; r < R; ++r)
      us[r * 256 + m] = part[(0 * R + r) * 256 + m] + part[(1 * R + r) * 256 + m] +
                        part[(2 * R + r) * 256 + m] + part[(3 * R + r) * 256 + m] - sm[BS + m];
  }
  __syncthreads();

  float4 ya[R];
#pragma unroll
  for (int r = 0; r < R; ++r) ya[r] = make_float4(0.f, 0.f, 0.f, 0.f);
  const float4* AAB = (const float4*)a.AAt;
#pragma unroll 2
  for (int mi = 0; mi < 64; ++mi) {
    float ur[R][4];
#pragma unroll
    for (int r = 0; r < R; ++r) *(float4*)ur[r] = *(const float4*)&us[r * 256 + mi * 4];
#pragma unroll
    for (int j = 0; j < 4; ++j) {
      const float4 w = AAB[(size_t)(mi * 4 + j) * (D / 4) + tid];
#pragma unroll
      for (int r = 0; r < R; ++r) {
        ya[r].x = fmaf(ur[r][j], w.x, ya[r].x);
        ya[r].y = fmaf(ur[r][j], w.y, ya[r].y);
        ya[r].z = fmaf(ur[r][j], w.z, ya[r].z);
        ya[r].w = fmaf(ur[r][j], w.w, ya[r].w);
      }
    }
  }

  float nmax = 0.f;
#pragma unroll
  for (int r = 0; r < R; ++r) {
    const float4 tv = *(const float4*)&ts[r * 1024 + tid * 4];
    float4 y;
    y.x = tv.x - ya[r].x; y.y = tv.y - ya[r].y;
    y.z = tv.z - ya[r].z; y.w = tv.w - ya[r].w;
    ((float4*)a.yout)[(size_t)(r0 + r) * (D / 4) + tid] = y;
    const float4 qv = *(const float4*)&qs[r * 1024 + tid * 4];
    float4 tn, qn;
    { const float yq = y.x + qv.x, xn = fmaxf(yq, 0.f); tn.x = xn + (tv.x - y.x); qn.x = yq - xn; }
    { const float yq = y.y + qv.y, xn = fmaxf(yq, 0.f); tn.y = xn + (tv.y - y.y); qn.y = yq - xn; }
    { const float yq = y.z + qv.z, xn = fmaxf(yq, 0.f); tn.z = xn + (tv.z - y.z); qn.z = yq - xn; }
    { const float yq = y.w + qv.w, xn = fmaxf(yq, 0.f); tn.w = xn + (tv.w - y.w); qn.w = yq - xn; }
    *(float4*)&ts[r * 1024 + tid * 4] = tn;
    *(float4*)&qs[r * 1024 + tid * 4] = qn;
    nmax = fmaxf(nmax, -y.x); nmax = fmaxf(nmax, -y.y);
    nmax = fmaxf(nmax, -y.z); nmax = fmaxf(nmax, -y.w);
  }
#pragma unroll
  for (int off = 32; off > 0; off >>= 1) nmax = fmaxf(nmax, __shfl_down(nmax, off));
  if ((tid & 63) == 0) sm[RED + (tid >> 6)] = nmax;
  __syncthreads();
}

// fence-free round: per-iteration sync via per-block posted err slots
template <int R>
__device__ void dyk_round(float* sm, const KArgs& a, int lid, int nblk, int base) {
  const int r0 = lid * R;
  dyk_state_init<R>(sm, a, r0);
  for (int it = 0; it < MAXIT; ++it) {
    dyk_iter<R>(sm, a, r0);
    if (threadIdx.x == 0) {
      const float bmax = fmaxf(fmaxf(sm[RED], sm[RED + 1]), fmaxf(sm[RED + 2], sm[RED + 3]));
      __hip_atomic_store(&a.errb[(size_t)(base + it) * GRID + lid],
                         __float_as_uint(bmax) | 0x80000000u,
                         __ATOMIC_RELAXED, __HIP_MEMORY_SCOPE_AGENT);
    }
    float v = 0.f;
    if (threadIdx.x < nblk) {
      unsigned u = __hip_atomic_load(&a.errb[(size_t)(base + it) * GRID + threadIdx.x],
                                     __ATOMIC_RELAXED, __HIP_MEMORY_SCOPE_AGENT);
      while (!(u & 0x80000000u)) {
        __builtin_amdgcn_s_sleep(1);
        u = __hip_atomic_load(&a.errb[(size_t)(base + it) * GRID + threadIdx.x],
                              __ATOMIC_RELAXED, __HIP_MEMORY_SCOPE_AGENT);
      }
      v = __uint_as_float(u & 0x7FFFFFFFu);
    }
#pragma unroll
    for (int off = 32; off > 0; off >>= 1) v = fmaxf(v, __shfl_down(v, off));
    __syncthreads();
    if ((threadIdx.x & 63) == 0) sm[RED + (threadIdx.x >> 6)] = v;
    __syncthreads();
    const float gmax = fmaxf(fmaxf(sm[RED], sm[RED + 1]), fmaxf(sm[RED + 2], sm[RED + 3]));
    __syncthreads();
    if (gmax < TOLV) break;
  }
}

// ---------------- the megakernel ----------------
__global__ __launch_bounds__(256, 1) void mega(KArgs a) {
  __shared__ alignas(16) float sm[SMF];
  const int bid = blockIdx.x;
  const int tid = threadIdx.x;
  unsigned genF = 0, genG = 0;

  // ---- joint init ----
  {
    const int gtid = bid * 256 + tid;
    for (int i = gtid; i < BSZ * D; i += GRID * 256) a.t[i] = -RHOV * a.c[i];
    if (gtid < D) a.perm[gtid] = gtid;
  }
  for (int vb = bid; vb < 384; vb += GRID) {
    if (vb < 256) ph_prep(sm, vb, a.L, a.Lam, a.F, a.Ybuf);
    else if (vb < 320) { const int tt = vb - 256; ph_transpose(sm, a.A, a.At, MC, D, tt & 3, tt >> 2); }
    else { const int tt = vb - 320; ph_transpose(sm, a.AA, a.AAt, D, MC, tt & 15, tt >> 4); }
  }
  if (bid == 0) {  // panel-0 diag tile was written by this very block (vb==0)
    __threadfence_block();
    __syncthreads();
    ph_lu_diag(sm, a.F, a.perm, a.rmap, 0);
  }
  fbar(a.slotsF, bid, GRID, ++genF);

  if (bid < NGB) {
    // ======== group B: LU (2 barriers/panel) + piggybacked forward solve ========
    unsigned* slotsB = a.slotsG;
    const int vbid = bid;
    for (int k = 0; k < NPAN; ++k) {
      const int rem = D - (k + 1) * NBK;
      const int nvb = (rem > 0) ? (rem + 255) / 256 : 0;
      // P1: leftperm | l21 | trsm | fsolve(k)
      const int ntask = k + 2 * nvb + 4;
      for (int vb = vbid; vb < ntask; vb += NGB) {
        if (vb < k) ph_leftperm(sm, a.F, a.rmap + k * 64, k, vb);
        else if (vb < k + nvb) ph_l21(sm, a.F, k, vb - k);
        else if (vb < k + 2 * nvb) ph_trsm(sm, a.F, a.rmap + k * 64, k, vb - k - nvb);
        else ph_fsolve(sm, a.F, a.Ybuf, k, vb - k - 2 * nvb);
      }
      fbar(slotsB, vbid, NGB, ++genG);
      // P2: gemm trailing | forward-solve tn | fused lu_diag(k+1) by block 0
      if (rem > 0) {
        const int nt = rem / 64;
        const int ntask2 = nt * nt + 16 * nt;
        for (int vb = vbid; vb < ntask2; vb += NGB) {
          if (vb < nt * nt) ph_gemm_nn(sm, a.F, k, vb % nt, vb / nt);
          else { const int t2 = vb - nt * nt; ph_tn(sm, a.F, a.Ybuf, k, (k + 1) * NBK, t2 & 15, t2 >> 4); }
        }
        if (vbid == 0) {
          __threadfence_block();
          __syncthreads();
          ph_lu_diag(sm, a.F, a.perm, a.rmap + (k + 1) * 64, k + 1);
        }
        fbar(slotsB, vbid, NGB, ++genG);
      }
    }
    // ---- backward solve (barrier-phase form, verified) ----
    for (int k = NPAN - 1; k >= 0; --k) {
      for (int vb = vbid; vb < 4; vb += NGB) ph_bsolve(sm, a.F, a.Ybuf, k, vb);
      fbar(slotsB, vbid, NGB, ++genG);
      if (k > 0) {
        for (int vb = vbid; vb < 16 * k; vb += NGB)
          ph_tn(sm, a.F, a.Ybuf, k, 0, vb & 15, vb >> 4);
        fbar(slotsB, vbid, NGB, ++genG);
      }
    }
    for (int vb = vbid; vb < 4 * D; vb += NGB) ph_scatter(a.Ybuf, a.Wm, a.perm, vb);
    fbar(a.slotsF, bid, GRID, ++genF);  // join: Wm published
  } else {
    // ======== group A: round-0 Dykstra (overlaps group B) ========
    dyk_round<4>(sm, a, bid - NGB, NGA, 0);
    fbar(a.slotsF, bid, GRID, ++genF);  // join
  }

  // ======== rounds 1,2: ph_round on B-blocks; Dykstra R=4 on A-blocks ========
  for (int r = 1; r < N_ROUNDS; ++r) {
    if (bid < 128) ph_round(sm, a.yout, a.Wm, a.c, a.t, bid & 15, bid >> 4);
    fbar(a.slotsF, bid, GRID, ++genF);  // t ready
    if (bid >= NGB) dyk_round<4>(sm, a, bid - NGB, NGA, r * MAXIT);
    if (r + 1 < N_ROUNDS)
      fbar(a.slotsF, bid, GRID, ++genF);  // yout ready for next ph_round
  }
}

extern "C" void kernel_launch(void* const* d_in, const int* in_sizes, int n_in,
                              void* d_out, int out_size, void* d_ws, size_t ws_size,
                              hipStream_t stream) {
  (void)in_sizes; (void)n_in; (void)out_size; (void)ws_size;
  KArgs a;
  a.c   = (const float*)d_in[0];
  a.A   = (const float*)d_in[1];
  a.b   = (const float*)d_in[2];
  a.AA  = (const float*)d_in[3];
  a.L   = (const float*)d_in[4];
  a.Lam = (const float*)d_in[5];
  a.yout = (float*)d_out;

  // ctrl region (zeroed every call; ws is NOT re-poisoned between replays)
  char* w = (char*)d_ws;
  a.slotsF = (unsigned*)w;                    // 256 x 64B
  a.slotsG = (unsigned*)(w + 16384);          // 128 x 64B (B domain)
  a.errb   = (unsigned*)(w + 32768);          // 90 x 256 posted-err slots
  a.rmap   = (int*)(w + 124928);              // 16 x 64 ints
  w += 131072;
  a.F    = (float*)w; w += (size_t)D * D * 4;
  a.Ybuf = (float*)w; w += (size_t)D * D * 4;
  a.Wm   = (float*)w; w += (size_t)D * D * 4;
  a.t    = (float*)w; w += (size_t)BSZ * D * 4;
  a.At   = (float*)w; w += (size_t)D * MC * 4;
  a.AAt  = (float*)w; w += (size_t)MC * D * 4;
  a.perm = (int*)w;   w += (size_t)D * 4;

  hipMemsetAsync(d_ws, 0, 131072, stream);
  mega<<<dim3(GRID), dim3(256), 0, stream>>>(a);
}